// Round 6
// baseline (2737.663 us; speedup 1.0000x reference)
//
#include <hip/hip_runtime.h>

#define LOG2E 1.4426950408889634f

// ---------------- ws layout (bytes) ----------------
#define WK_OFF   ((size_t)0)          // wk_eff f32 [8][512]
#define KB_OFF   ((size_t)16384)      // kbias f32 [8]
#define Q2_OFF   ((size_t)16416)      // q2 f32 [512]
#define SEG_OFF  ((size_t)18464)      // seg i32 [4097]
#define S_OFF    ((size_t)34880)      // S_ws bf16 [8][4096][512]
#define ATTN_OFF ((size_t)33589312)   // attn bf16 [4096][512]
#define WVHI_OFF ((size_t)37783616)   // Wv hi bf16 [512*512]
#define WVLO_OFF ((size_t)38307904)
#define WOHI_OFF ((size_t)38832192)
#define WOLO_OFF ((size_t)39356480)
#define WS_NEEDED ((size_t)39880768)
// probe: duplicate k_main output region (32 MB)
#define SDUP_OFF ((size_t)39880768)
#define WS_PROBE (SDUP_OFF + (size_t)8*4096*512*2)

typedef __bf16 bf16x8 __attribute__((ext_vector_type(8)));
typedef float f32x4 __attribute__((ext_vector_type(4)));

__device__ __forceinline__ float readlane_f(float v, int l) {
  return __int_as_float(__builtin_amdgcn_readlane(__float_as_int(v), l));
}

__device__ __forceinline__ unsigned short f2bf(float x) {
  unsigned u = __float_as_uint(x);
  unsigned r = (u + 0x7fffu + ((u >> 16) & 1u)) >> 16;
  return (unsigned short)r;
}

__device__ __forceinline__ float bf2f(unsigned short h) {
  return __uint_as_float((unsigned)h << 16);
}

// ---------------- K0: fused prep (W hi/lo split + seg lower_bound + q2) ----------------
__global__ __launch_bounds__(256) void k_prep(
    const float* __restrict__ Wv, const float* __restrict__ Wo,
    unsigned short* __restrict__ wvhi, unsigned short* __restrict__ wvlo,
    unsigned short* __restrict__ wohi, unsigned short* __restrict__ wolo,
    const void* __restrict__ batch, int n, int* __restrict__ seg,
    const float* __restrict__ qry, const float* __restrict__ Wq,
    const float* __restrict__ bq, float* __restrict__ q2) {
  int bx = blockIdx.x;
  if (bx < 1024) {
    int i = bx * 256 + threadIdx.x;
    float v = Wv[i];
    unsigned short h = f2bf(v);
    wvhi[i] = h;
    wvlo[i] = f2bf(v - bf2f(h));
    float o = Wo[i];
    unsigned short h2 = f2bf(o);
    wohi[i] = h2;
    wolo[i] = f2bf(o - bf2f(h2));
  } else if (bx < 1041) {
    int b = (bx - 1024) * 256 + threadIdx.x;
    if (b > 4096) return;
    const int* b32 = (const int*)batch;
    const long long* b64 = (const long long*)batch;
    bool is64 = (b32[n - 1] == 0);
    int lo = 0, hi = n;
    while (lo < hi) {
      int mid = (lo + hi) >> 1;
      long long v = is64 ? b64[mid] : (long long)b32[mid];
      if (v < (long long)b) lo = mid + 1; else hi = mid;
    }
    seg[b] = lo;
  } else {
    int d = (bx - 1041) * 256 + threadIdx.x;
    const float4* q4 = (const float4*)qry;
    const float4* w4 = (const float4*)(Wq + (size_t)d * 512);
    float acc = 0.f;
    #pragma unroll 4
    for (int j = 0; j < 128; ++j) {
      float4 a = q4[j], b = w4[j];
      acc += a.x * b.x + a.y * b.y + a.z * b.z + a.w * b.w;
    }
    q2[d] = (acc + bq[d]) * (0.125f * LOG2E);
  }
}

// ---------------- K1: wk_eff + kbias ----------------
__global__ __launch_bounds__(256) void k_wk(const float* __restrict__ Wk,
                                            const float* __restrict__ bk,
                                            const float* __restrict__ q2,
                                            float* __restrict__ wk,
                                            float* __restrict__ kb) {
  if (blockIdx.x == 16) {
    int h = threadIdx.x;
    if (h < 8) {
      float acc = 0.f;
      for (int dd = 0; dd < 64; ++dd) acc += q2[h * 64 + dd] * bk[h * 64 + dd];
      kb[h] = acc;
    }
    return;
  }
  int id = blockIdx.x * 256 + threadIdx.x;
  int h = id >> 9, e = id & 511;
  float acc = 0.f;
  #pragma unroll 4
  for (int dd = 0; dd < 64; ++dd)
    acc += q2[h * 64 + dd] * Wk[(size_t)(h * 64 + dd) * 512 + e];
  wk[id] = acc;
}

// ---------------- K2: fused scores + softmax + pooling (branch-free pipeline) ----------------
// Per wave: 2 nodes/step, stride 8 across 4 waves, triple-buffered 2-deep prefetch.
// Score reduce: register-only value-halving shfl_xor butterfly (no LDS in loop).
// Out-of-range nodes get clamped loads + zero weight (uniform control flow).

#define PREF(T, B0, B1, B2, B3)                          \
  {                                                      \
    int i0_ = base + 8 * (T);                            \
    int a_ = i0_ < em1 ? i0_ : em1;                      \
    int c_ = i0_ + 1 < em1 ? i0_ + 1 : em1;              \
    size_t o_ = (size_t)a_ * 128 + lane;                 \
    B0 = emb4[o_]; B1 = emb4[o_ + 64];                   \
    size_t o2_ = (size_t)c_ * 128 + lane;                \
    B2 = emb4[o2_]; B3 = emb4[o2_ + 64];                 \
  }

#define PROC(T, B0, B1, B2, B3)                                                   \
  {                                                                               \
    float p[16];                                                                  \
    _Pragma("unroll")                                                             \
    for (int h = 0; h < 8; ++h) {                                                 \
      float4 wa = wka[h], wb = wkb[h];                                            \
      p[h] = B0.x * wa.x + B0.y * wa.y + B0.z * wa.z + B0.w * wa.w +              \
             B1.x * wb.x + B1.y * wb.y + B1.z * wb.z + B1.w * wb.w;               \
      p[8 + h] = B2.x * wa.x + B2.y * wa.y + B2.z * wa.z + B2.w * wa.w +          \
                 B3.x * wb.x + B3.y * wb.y + B3.z * wb.z + B3.w * wb.w;           \
    }                                                                             \
    float q[8];                                                                   \
    _Pragma("unroll")                                                             \
    for (int i2 = 0; i2 < 8; ++i2) {                                              \
      float keep = (lane & 1) ? p[2 * i2 + 1] : p[2 * i2];                        \
      float send = (lane & 1) ? p[2 * i2] : p[2 * i2 + 1];                        \
      q[i2] = keep + __shfl_xor(send, 1);                                         \
    }                                                                             \
    float r[4];                                                                   \
    _Pragma("unroll")                                                             \
    for (int i2 = 0; i2 < 4; ++i2) {                                              \
      float keep = (lane & 2) ? q[2 * i2 + 1] : q[2 * i2];                        \
      float send = (lane & 2) ? q[2 * i2] : q[2 * i2 + 1];                        \
      r[i2] = keep + __shfl_xor(send, 2);                                         \
    }                                                                             \
    float s2[2];                                                                  \
    _Pragma("unroll")                                                             \
    for (int i2 = 0; i2 < 2; ++i2) {                                              \
      float keep = (lane & 4) ? r[2 * i2 + 1] : r[2 * i2];                        \
      float send = (lane & 4) ? r[2 * i2] : r[2 * i2 + 1];                        \
      s2[i2] = keep + __shfl_xor(send, 4);                                        \
    }                                                                             \
    s2[0] += __shfl_xor(s2[0], 8);  s2[1] += __shfl_xor(s2[1], 8);                \
    s2[0] += __shfl_xor(s2[0], 16); s2[1] += __shfl_xor(s2[1], 16);               \
    s2[0] += __shfl_xor(s2[0], 32); s2[1] += __shfl_xor(s2[1], 32);               \
    int n0_ = base + 8 * (T);                                                     \
    float w0 = (n0_ < e2) ? exp2f(s2[0] + kbl) : 0.f;                             \
    float w1 = (n0_ + 1 < e2) ? exp2f(s2[1] + kbl) : 0.f;                         \
    dn += w0 + w1;                                                                \
    _Pragma("unroll")                                                             \
    for (int h = 0; h < 8; ++h) {                                                 \
      float f0 = readlane_f(w0, h), f1 = readlane_f(w1, h);                       \
      Sa[h].x += f0 * B0.x + f1 * B2.x; Sa[h].y += f0 * B0.y + f1 * B2.y;         \
      Sa[h].z += f0 * B0.z + f1 * B2.z; Sa[h].w += f0 * B0.w + f1 * B2.w;         \
      Sb[h].x += f0 * B1.x + f1 * B3.x; Sb[h].y += f0 * B1.y + f1 * B3.y;         \
      Sb[h].z += f0 * B1.z + f1 * B3.z; Sb[h].w += f0 * B1.w + f1 * B3.w;         \
    }                                                                             \
  }

__global__ __launch_bounds__(256, 2) void k_main(const float* __restrict__ emb,
                                                 const int* __restrict__ seg,
                                                 const float* __restrict__ wk,
                                                 const float* __restrict__ kb,
                                                 unsigned short* __restrict__ S_out,
                                                 int reps) {
  __shared__ float sm[8232];
  const int tid = threadIdx.x;
  const int lane = tid & 63, wave = tid >> 6;
  const int b = blockIdx.x;
  const int s = seg[b], e2 = seg[b + 1];
  const int nt = e2 - s;
  const int em1 = e2 - 1;

  float4 wka[8], wkb[8];
  #pragma unroll
  for (int h = 0; h < 8; ++h) {
    wka[h] = *(const float4*)(wk + h * 512 + 4 * lane);
    wkb[h] = *(const float4*)(wk + h * 512 + 256 + 4 * lane);
  }
  const float kbl = kb[lane & 7];
  const float4* emb4 = (const float4*)emb;
  const int base = s + wave * 2;

  for (int rep = 0; rep < reps; ++rep) {
    float4 Sa[8], Sb[8];
    #pragma unroll
    for (int h = 0; h < 8; ++h) {
      Sa[h] = make_float4(0.f, 0.f, 0.f, 0.f);
      Sb[h] = make_float4(0.f, 0.f, 0.f, 0.f);
    }
    float dn = 0.f;

    if (nt > 0) {
      const int it = (nt + 7) >> 3;
      float4 A0, A1, A2, A3, B0, B1, B2, B3, C0, C1, C2, C3;
      PREF(0, A0, A1, A2, A3);
      PREF(1, B0, B1, B2, B3);
      int t = 0;
      while (true) {
        if (t >= it) break;
        PREF(t + 2, C0, C1, C2, C3);
        PROC(t, A0, A1, A2, A3);
        ++t;
        if (t >= it) break;
        PREF(t + 2, A0, A1, A2, A3);
        PROC(t, B0, B1, B2, B3);
        ++t;
        if (t >= it) break;
        PREF(t + 2, B0, B1, B2, B3);
        PROC(t, C0, C1, C2, C3);
        ++t;
      }
    }
    __syncthreads();

    if (lane < 8) sm[8192 + wave * 8 + lane] = dn;
    __syncthreads();
    if (tid < 8) {
      float d = sm[8192 + tid] + sm[8200 + tid] + sm[8208 + tid] + sm[8216 + tid];
      sm[8224 + tid] = (d > 0.f) ? 1.f / d : 0.f;
    }
    __syncthreads();

    #pragma unroll
    for (int h = 0; h < 8; ++h)
      *(float4*)&sm[wave * 2048 + h * 256 + 4 * lane] = Sa[h];
    __syncthreads();
    #pragma unroll
    for (int h = 0; h < 8; ++h) {
      float v = (sm[h * 256 + tid] + sm[2048 + h * 256 + tid] +
                 sm[4096 + h * 256 + tid] + sm[6144 + h * 256 + tid]) * sm[8224 + h];
      S_out[((size_t)h * 4096 + b) * 512 + tid] = f2bf(v);
    }
    __syncthreads();
    #pragma unroll
    for (int h = 0; h < 8; ++h)
      *(float4*)&sm[wave * 2048 + h * 256 + 4 * lane] = Sb[h];
    __syncthreads();
    #pragma unroll
    for (int h = 0; h < 8; ++h) {
      float v = (sm[h * 256 + tid] + sm[2048 + h * 256 + tid] +
                 sm[4096 + h * 256 + tid] + sm[6144 + h * 256 + tid]) * sm[8224 + h];
      S_out[((size_t)h * 4096 + b) * 512 + 256 + tid] = f2bf(v);
    }
    __syncthreads();
  }
}

// ---------------- K3/K4: MFMA NT GEMM ----------------
template <bool C_BF16>
__global__ __launch_bounds__(256) void k_gemm_mfma(
    const unsigned short* __restrict__ A, size_t a_cb_stride,
    const unsigned short* __restrict__ Whi, const unsigned short* __restrict__ Wlo,
    const float* __restrict__ bias, void* __restrict__ Cv) {
  const int t = threadIdx.x;
  const int lane = t & 63, wvid = t >> 6;
  const int wr = wvid >> 1, wc = wvid & 1;
  const int row16 = lane & 15;
  const int k8 = (lane >> 4) * 8;
  const int mbase = blockIdx.x * 64 + wr * 32;
  const int nbase = blockIdx.y * 64 + wc * 32;

  const unsigned short* Ap = A + (size_t)blockIdx.y * a_cb_stride +
                             (size_t)(mbase + row16) * 512 + k8;
  const unsigned short* Wh = Whi + (size_t)(nbase + row16) * 512 + k8;
  const unsigned short* Wl = Wlo + (size_t)(nbase + row16) * 512 + k8;

  f32x4 acc[2][2] = {};

  #pragma unroll 4
  for (int kk = 0; kk < 512; kk += 32) {
    bf16x8 a0 = *(const bf16x8*)(Ap + kk);
    bf16x8 a1 = *(const bf16x8*)(Ap + 16 * 512 + kk);
    bf16x8 h0 = *(const bf16x8*)(Wh + kk);
    bf16x8 h1 = *(const bf16x8*)(Wh + 16 * 512 + kk);
    bf16x8 l0 = *(const bf16x8*)(Wl + kk);
    bf16x8 l1 = *(const bf16x8*)(Wl + 16 * 512 + kk);
    acc[0][0] = __builtin_amdgcn_mfma_f32_16x16x32_bf16(a0, h0, acc[0][0], 0, 0, 0);
    acc[0][1] = __builtin_amdgcn_mfma_f32_16x16x32_bf16(a0, h1, acc[0][1], 0, 0, 0);
    acc[1][0] = __builtin_amdgcn_mfma_f32_16x16x32_bf16(a1, h0, acc[1][0], 0, 0, 0);
    acc[1][1] = __builtin_amdgcn_mfma_f32_16x16x32_bf16(a1, h1, acc[1][1], 0, 0, 0);
    acc[0][0] = __builtin_amdgcn_mfma_f32_16x16x32_bf16(a0, l0, acc[0][0], 0, 0, 0);
    acc[0][1] = __builtin_amdgcn_mfma_f32_16x16x32_bf16(a0, l1, acc[0][1], 0, 0, 0);
    acc[1][0] = __builtin_amdgcn_mfma_f32_16x16x32_bf16(a1, l0, acc[1][0], 0, 0, 0);
    acc[1][1] = __builtin_amdgcn_mfma_f32_16x16x32_bf16(a1, l1, acc[1][1], 0, 0, 0);
  }

  const int r4 = (lane >> 4) * 4;
  #pragma unroll
  for (int c = 0; c < 2; ++c) {
    const float bc = bias[nbase + c * 16 + row16];
    #pragma unroll
    for (int r = 0; r < 2; ++r) {
      #pragma unroll
      for (int j = 0; j < 4; ++j) {
        float v = acc[r][c][j] + bc;
        size_t row = (size_t)(mbase + r * 16 + r4 + j);
        size_t col = (size_t)(nbase + c * 16 + row16);
        if (C_BF16)
          ((unsigned short*)Cv)[row * 512 + col] = f2bf(v);
        else
          ((float*)Cv)[row * 512 + col] = v;
      }
    }
  }
}

// ---------------- launcher ----------------
extern "C" void kernel_launch(void* const* d_in, const int* in_sizes, int n_in,
                              void* d_out, int out_size, void* d_ws, size_t ws_size,
                              hipStream_t stream) {
  const float* emb   = (const float*)d_in[0];
  const void*  batch = d_in[1];
  const float* qry   = (const float*)d_in[2];
  const float* Wq    = (const float*)d_in[3];
  const float* bq    = (const float*)d_in[4];
  const float* Wk    = (const float*)d_in[5];
  const float* bk    = (const float*)d_in[6];
  const float* Wv    = (const float*)d_in[7];
  const float* bv    = (const float*)d_in[8];
  const float* Wo    = (const float*)d_in[9];
  const float* bo    = (const float*)d_in[10];
  const int N = in_sizes[1];

  if (ws_size < WS_NEEDED) return;

  char* ws = (char*)d_ws;
  float* wk_eff = (float*)(ws + WK_OFF);
  float* kbias  = (float*)(ws + KB_OFF);
  float* q2     = (float*)(ws + Q2_OFF);
  int*   seg    = (int*)(ws + SEG_OFF);
  unsigned short* S_ws = (unsigned short*)(ws + S_OFF);
  unsigned short* attn = (unsigned short*)(ws + ATTN_OFF);
  unsigned short* wvhi = (unsigned short*)(ws + WVHI_OFF);
  unsigned short* wvlo = (unsigned short*)(ws + WVLO_OFF);
  unsigned short* wohi = (unsigned short*)(ws + WOHI_OFF);
  unsigned short* wolo = (unsigned short*)(ws + WOLO_OFF);

  k_prep<<<1043, 256, 0, stream>>>(Wv, Wo, wvhi, wvlo, wohi, wolo,
                                   batch, N, seg, qry, Wq, bq, q2);
  k_wk  <<<17, 256, 0, stream>>>(Wk, bk, q2, wk_eff, kbias);
  k_main<<<4096, 256, 0, stream>>>(emb, seg, wk_eff, kbias, S_ws, 1);

  // ---- PROBE: one dispatch with 4 internal repetitions into scratch.
  // Duration ~4x k_main -> surfaces in rocprof top-5 with its counters
  // (VGPR_Count for spill check, hbm_gbps for achieved BW).
  if (ws_size >= WS_PROBE) {
    unsigned short* S_dup = (unsigned short*)(ws + SDUP_OFF);
    k_main<<<4096, 256, 0, stream>>>(emb, seg, wk_eff, kbias, S_dup, 4);
  }

  dim3 g(64, 8);
  k_gemm_mfma<true ><<<g, 256, 0, stream>>>(S_ws, (size_t)4096 * 512, wvhi, wvlo, bv, attn);
  k_gemm_mfma<false><<<g, 256, 0, stream>>>(attn, 0, wohi, wolo, bo, d_out);
}

// Round 7
// 2728.692 us; speedup vs baseline: 1.0033x; 1.0033x over previous
//
#include <hip/hip_runtime.h>

#define LOG2E 1.4426950408889634f

// ---------------- ws layout (bytes) ----------------
#define WK_OFF   ((size_t)0)          // wk_eff f32 [8][512]
#define KB_OFF   ((size_t)16384)      // kbias f32 [8]
#define Q2_OFF   ((size_t)16416)      // q2 f32 [512]
#define SEG_OFF  ((size_t)18464)      // seg i32 [4097]
#define S_OFF    ((size_t)34880)      // S_ws bf16 [8][4096][512]
#define ATTN_OFF ((size_t)33589312)   // attn bf16 [4096][512]
#define WVHI_OFF ((size_t)37783616)   // Wv hi bf16 [512*512]
#define WVLO_OFF ((size_t)38307904)
#define WOHI_OFF ((size_t)38832192)
#define WOLO_OFF ((size_t)39356480)
#define WS_NEEDED ((size_t)39880768)
// probe: duplicate k_main output region (32 MB)
#define SDUP_OFF ((size_t)39880768)
#define WS_PROBE (SDUP_OFF + (size_t)8*4096*512*2)

typedef __bf16 bf16x8 __attribute__((ext_vector_type(8)));
typedef float f32x4 __attribute__((ext_vector_type(4)));

__device__ __forceinline__ float readlane_f(float v, int l) {
  return __int_as_float(__builtin_amdgcn_readlane(__float_as_int(v), l));
}

__device__ __forceinline__ unsigned short f2bf(float x) {
  unsigned u = __float_as_uint(x);
  unsigned r = (u + 0x7fffu + ((u >> 16) & 1u)) >> 16;
  return (unsigned short)r;
}

__device__ __forceinline__ float bf2f(unsigned short h) {
  return __uint_as_float((unsigned)h << 16);
}

// ---------------- K0: fused prep (W hi/lo split + seg lower_bound + q2) ----------------
__global__ __launch_bounds__(256) void k_prep(
    const float* __restrict__ Wv, const float* __restrict__ Wo,
    unsigned short* __restrict__ wvhi, unsigned short* __restrict__ wvlo,
    unsigned short* __restrict__ wohi, unsigned short* __restrict__ wolo,
    const void* __restrict__ batch, int n, int* __restrict__ seg,
    const float* __restrict__ qry, const float* __restrict__ Wq,
    const float* __restrict__ bq, float* __restrict__ q2) {
  int bx = blockIdx.x;
  if (bx < 1024) {
    int i = bx * 256 + threadIdx.x;
    float v = Wv[i];
    unsigned short h = f2bf(v);
    wvhi[i] = h;
    wvlo[i] = f2bf(v - bf2f(h));
    float o = Wo[i];
    unsigned short h2 = f2bf(o);
    wohi[i] = h2;
    wolo[i] = f2bf(o - bf2f(h2));
  } else if (bx < 1041) {
    int b = (bx - 1024) * 256 + threadIdx.x;
    if (b > 4096) return;
    const int* b32 = (const int*)batch;
    const long long* b64 = (const long long*)batch;
    bool is64 = (b32[n - 1] == 0);
    int lo = 0, hi = n;
    while (lo < hi) {
      int mid = (lo + hi) >> 1;
      long long v = is64 ? b64[mid] : (long long)b32[mid];
      if (v < (long long)b) lo = mid + 1; else hi = mid;
    }
    seg[b] = lo;
  } else {
    int d = (bx - 1041) * 256 + threadIdx.x;
    const float4* q4 = (const float4*)qry;
    const float4* w4 = (const float4*)(Wq + (size_t)d * 512);
    float acc = 0.f;
    #pragma unroll 4
    for (int j = 0; j < 128; ++j) {
      float4 a = q4[j], b = w4[j];
      acc += a.x * b.x + a.y * b.y + a.z * b.z + a.w * b.w;
    }
    q2[d] = (acc + bq[d]) * (0.125f * LOG2E);
  }
}

// ---------------- K1: wk_eff + kbias ----------------
__global__ __launch_bounds__(256) void k_wk(const float* __restrict__ Wk,
                                            const float* __restrict__ bk,
                                            const float* __restrict__ q2,
                                            float* __restrict__ wk,
                                            float* __restrict__ kb) {
  if (blockIdx.x == 16) {
    int h = threadIdx.x;
    if (h < 8) {
      float acc = 0.f;
      for (int dd = 0; dd < 64; ++dd) acc += q2[h * 64 + dd] * bk[h * 64 + dd];
      kb[h] = acc;
    }
    return;
  }
  int id = blockIdx.x * 256 + threadIdx.x;
  int h = id >> 9, e = id & 511;
  float acc = 0.f;
  #pragma unroll 4
  for (int dd = 0; dd < 64; ++dd)
    acc += q2[h * 64 + dd] * Wk[(size_t)(h * 64 + dd) * 512 + e];
  wk[id] = acc;
}

// ---------------- K2: fused scores + softmax + pooling (branch-free pipeline) ----------------
// Per wave: 2 nodes/step, stride 8 across 4 waves, triple-buffered 2-deep prefetch.
// Score reduce: register-only value-halving shfl_xor butterfly (no LDS in loop).
// Out-of-range nodes get clamped loads + zero weight (uniform control flow).

#define PREF(T, B0, B1, B2, B3)                          \
  {                                                      \
    int i0_ = base + 8 * (T);                            \
    int a_ = i0_ < em1 ? i0_ : em1;                      \
    int c_ = i0_ + 1 < em1 ? i0_ + 1 : em1;              \
    size_t o_ = (size_t)a_ * 128 + lane;                 \
    B0 = emb4[o_]; B1 = emb4[o_ + 64];                   \
    size_t o2_ = (size_t)c_ * 128 + lane;                \
    B2 = emb4[o2_]; B3 = emb4[o2_ + 64];                 \
  }

#define PROC(T, B0, B1, B2, B3)                                                   \
  {                                                                               \
    float p[16];                                                                  \
    _Pragma("unroll")                                                             \
    for (int h = 0; h < 8; ++h) {                                                 \
      float4 wa = wka[h], wb = wkb[h];                                            \
      p[h] = B0.x * wa.x + B0.y * wa.y + B0.z * wa.z + B0.w * wa.w +              \
             B1.x * wb.x + B1.y * wb.y + B1.z * wb.z + B1.w * wb.w;               \
      p[8 + h] = B2.x * wa.x + B2.y * wa.y + B2.z * wa.z + B2.w * wa.w +          \
                 B3.x * wb.x + B3.y * wb.y + B3.z * wb.z + B3.w * wb.w;           \
    }                                                                             \
    float q[8];                                                                   \
    _Pragma("unroll")                                                             \
    for (int i2 = 0; i2 < 8; ++i2) {                                              \
      float keep = (lane & 1) ? p[2 * i2 + 1] : p[2 * i2];                        \
      float send = (lane & 1) ? p[2 * i2] : p[2 * i2 + 1];                        \
      q[i2] = keep + __shfl_xor(send, 1);                                         \
    }                                                                             \
    float r[4];                                                                   \
    _Pragma("unroll")                                                             \
    for (int i2 = 0; i2 < 4; ++i2) {                                              \
      float keep = (lane & 2) ? q[2 * i2 + 1] : q[2 * i2];                        \
      float send = (lane & 2) ? q[2 * i2] : q[2 * i2 + 1];                        \
      r[i2] = keep + __shfl_xor(send, 2);                                         \
    }                                                                             \
    float s2[2];                                                                  \
    _Pragma("unroll")                                                             \
    for (int i2 = 0; i2 < 2; ++i2) {                                              \
      float keep = (lane & 4) ? r[2 * i2 + 1] : r[2 * i2];                        \
      float send = (lane & 4) ? r[2 * i2] : r[2 * i2 + 1];                        \
      s2[i2] = keep + __shfl_xor(send, 4);                                        \
    }                                                                             \
    s2[0] += __shfl_xor(s2[0], 8);  s2[1] += __shfl_xor(s2[1], 8);                \
    s2[0] += __shfl_xor(s2[0], 16); s2[1] += __shfl_xor(s2[1], 16);               \
    s2[0] += __shfl_xor(s2[0], 32); s2[1] += __shfl_xor(s2[1], 32);               \
    int n0_ = base + 8 * (T);                                                     \
    float w0 = (n0_ < e2) ? exp2f(s2[0] + kbl) : 0.f;                             \
    float w1 = (n0_ + 1 < e2) ? exp2f(s2[1] + kbl) : 0.f;                         \
    dn += w0 + w1;                                                                \
    _Pragma("unroll")                                                             \
    for (int h = 0; h < 8; ++h) {                                                 \
      float f0 = readlane_f(w0, h), f1 = readlane_f(w1, h);                       \
      Sa[h].x += f0 * B0.x + f1 * B2.x; Sa[h].y += f0 * B0.y + f1 * B2.y;         \
      Sa[h].z += f0 * B0.z + f1 * B2.z; Sa[h].w += f0 * B0.w + f1 * B2.w;         \
      Sb[h].x += f0 * B1.x + f1 * B3.x; Sb[h].y += f0 * B1.y + f1 * B3.y;         \
      Sb[h].z += f0 * B1.z + f1 * B3.z; Sb[h].w += f0 * B1.w + f1 * B3.w;         \
    }                                                                             \
  }

__global__ __launch_bounds__(256, 2) void k_main(const float* __restrict__ emb,
                                                 const int* __restrict__ seg,
                                                 const float* __restrict__ wk,
                                                 const float* __restrict__ kb,
                                                 unsigned short* __restrict__ S_out,
                                                 int reps) {
  __shared__ float sm[8232];
  const int tid = threadIdx.x;
  const int lane = tid & 63, wave = tid >> 6;
  const int b = blockIdx.x;
  const int s = seg[b], e2 = seg[b + 1];
  const int nt = e2 - s;
  const int em1 = e2 - 1;

  float4 wka[8], wkb[8];
  #pragma unroll
  for (int h = 0; h < 8; ++h) {
    wka[h] = *(const float4*)(wk + h * 512 + 4 * lane);
    wkb[h] = *(const float4*)(wk + h * 512 + 256 + 4 * lane);
  }
  const float kbl = kb[lane & 7];
  const float4* emb4 = (const float4*)emb;
  const int base = s + wave * 2;

  for (int rep = 0; rep < reps; ++rep) {
    float4 Sa[8], Sb[8];
    #pragma unroll
    for (int h = 0; h < 8; ++h) {
      Sa[h] = make_float4(0.f, 0.f, 0.f, 0.f);
      Sb[h] = make_float4(0.f, 0.f, 0.f, 0.f);
    }
    float dn = 0.f;

    if (nt > 0) {
      const int it = (nt + 7) >> 3;
      float4 A0, A1, A2, A3, B0, B1, B2, B3, C0, C1, C2, C3;
      PREF(0, A0, A1, A2, A3);
      PREF(1, B0, B1, B2, B3);
      int t = 0;
      while (true) {
        if (t >= it) break;
        PREF(t + 2, C0, C1, C2, C3);
        PROC(t, A0, A1, A2, A3);
        ++t;
        if (t >= it) break;
        PREF(t + 2, A0, A1, A2, A3);
        PROC(t, B0, B1, B2, B3);
        ++t;
        if (t >= it) break;
        PREF(t + 2, B0, B1, B2, B3);
        PROC(t, C0, C1, C2, C3);
        ++t;
      }
    }
    __syncthreads();

    if (lane < 8) sm[8192 + wave * 8 + lane] = dn;
    __syncthreads();
    if (tid < 8) {
      float d = sm[8192 + tid] + sm[8200 + tid] + sm[8208 + tid] + sm[8216 + tid];
      sm[8224 + tid] = (d > 0.f) ? 1.f / d : 0.f;
    }
    __syncthreads();

    #pragma unroll
    for (int h = 0; h < 8; ++h)
      *(float4*)&sm[wave * 2048 + h * 256 + 4 * lane] = Sa[h];
    __syncthreads();
    #pragma unroll
    for (int h = 0; h < 8; ++h) {
      float v = (sm[h * 256 + tid] + sm[2048 + h * 256 + tid] +
                 sm[4096 + h * 256 + tid] + sm[6144 + h * 256 + tid]) * sm[8224 + h];
      S_out[((size_t)h * 4096 + b) * 512 + tid] = f2bf(v);
    }
    __syncthreads();
    #pragma unroll
    for (int h = 0; h < 8; ++h)
      *(float4*)&sm[wave * 2048 + h * 256 + 4 * lane] = Sb[h];
    __syncthreads();
    #pragma unroll
    for (int h = 0; h < 8; ++h) {
      float v = (sm[h * 256 + tid] + sm[2048 + h * 256 + tid] +
                 sm[4096 + h * 256 + tid] + sm[6144 + h * 256 + tid]) * sm[8224 + h];
      S_out[((size_t)h * 4096 + b) * 512 + 256 + tid] = f2bf(v);
    }
    __syncthreads();
  }
}

// ---------------- K3/K4: MFMA NT GEMM ----------------
template <bool C_BF16>
__global__ __launch_bounds__(256) void k_gemm_mfma(
    const unsigned short* __restrict__ A, size_t a_cb_stride,
    const unsigned short* __restrict__ Whi, const unsigned short* __restrict__ Wlo,
    const float* __restrict__ bias, void* __restrict__ Cv) {
  const int t = threadIdx.x;
  const int lane = t & 63, wvid = t >> 6;
  const int wr = wvid >> 1, wc = wvid & 1;
  const int row16 = lane & 15;
  const int k8 = (lane >> 4) * 8;
  const int mbase = blockIdx.x * 64 + wr * 32;
  const int nbase = blockIdx.y * 64 + wc * 32;

  const unsigned short* Ap = A + (size_t)blockIdx.y * a_cb_stride +
                             (size_t)(mbase + row16) * 512 + k8;
  const unsigned short* Wh = Whi + (size_t)(nbase + row16) * 512 + k8;
  const unsigned short* Wl = Wlo + (size_t)(nbase + row16) * 512 + k8;

  f32x4 acc[2][2] = {};

  #pragma unroll 4
  for (int kk = 0; kk < 512; kk += 32) {
    bf16x8 a0 = *(const bf16x8*)(Ap + kk);
    bf16x8 a1 = *(const bf16x8*)(Ap + 16 * 512 + kk);
    bf16x8 h0 = *(const bf16x8*)(Wh + kk);
    bf16x8 h1 = *(const bf16x8*)(Wh + 16 * 512 + kk);
    bf16x8 l0 = *(const bf16x8*)(Wl + kk);
    bf16x8 l1 = *(const bf16x8*)(Wl + 16 * 512 + kk);
    acc[0][0] = __builtin_amdgcn_mfma_f32_16x16x32_bf16(a0, h0, acc[0][0], 0, 0, 0);
    acc[0][1] = __builtin_amdgcn_mfma_f32_16x16x32_bf16(a0, h1, acc[0][1], 0, 0, 0);
    acc[1][0] = __builtin_amdgcn_mfma_f32_16x16x32_bf16(a1, h0, acc[1][0], 0, 0, 0);
    acc[1][1] = __builtin_amdgcn_mfma_f32_16x16x32_bf16(a1, h1, acc[1][1], 0, 0, 0);
    acc[0][0] = __builtin_amdgcn_mfma_f32_16x16x32_bf16(a0, l0, acc[0][0], 0, 0, 0);
    acc[0][1] = __builtin_amdgcn_mfma_f32_16x16x32_bf16(a0, l1, acc[0][1], 0, 0, 0);
    acc[1][0] = __builtin_amdgcn_mfma_f32_16x16x32_bf16(a1, l0, acc[1][0], 0, 0, 0);
    acc[1][1] = __builtin_amdgcn_mfma_f32_16x16x32_bf16(a1, l1, acc[1][1], 0, 0, 0);
  }

  const int r4 = (lane >> 4) * 4;
  #pragma unroll
  for (int c = 0; c < 2; ++c) {
    const float bc = bias[nbase + c * 16 + row16];
    #pragma unroll
    for (int r = 0; r < 2; ++r) {
      #pragma unroll
      for (int j = 0; j < 4; ++j) {
        float v = acc[r][c][j] + bc;
        size_t row = (size_t)(mbase + r * 16 + r4 + j);
        size_t col = (size_t)(nbase + c * 16 + row16);
        if (C_BF16)
          ((unsigned short*)Cv)[row * 512 + col] = f2bf(v);
        else
          ((float*)Cv)[row * 512 + col] = v;
      }
    }
  }
}

// ---------------- launcher ----------------
extern "C" void kernel_launch(void* const* d_in, const int* in_sizes, int n_in,
                              void* d_out, int out_size, void* d_ws, size_t ws_size,
                              hipStream_t stream) {
  const float* emb   = (const float*)d_in[0];
  const void*  batch = d_in[1];
  const float* qry   = (const float*)d_in[2];
  const float* Wq    = (const float*)d_in[3];
  const float* bq    = (const float*)d_in[4];
  const float* Wk    = (const float*)d_in[5];
  const float* bk    = (const float*)d_in[6];
  const float* Wv    = (const float*)d_in[7];
  const float* bv    = (const float*)d_in[8];
  const float* Wo    = (const float*)d_in[9];
  const float* bo    = (const float*)d_in[10];
  const int N = in_sizes[1];

  if (ws_size < WS_NEEDED) return;

  char* ws = (char*)d_ws;
  float* wk_eff = (float*)(ws + WK_OFF);
  float* kbias  = (float*)(ws + KB_OFF);
  float* q2     = (float*)(ws + Q2_OFF);
  int*   seg    = (int*)(ws + SEG_OFF);
  unsigned short* S_ws = (unsigned short*)(ws + S_OFF);
  unsigned short* attn = (unsigned short*)(ws + ATTN_OFF);
  unsigned short* wvhi = (unsigned short*)(ws + WVHI_OFF);
  unsigned short* wvlo = (unsigned short*)(ws + WVLO_OFF);
  unsigned short* wohi = (unsigned short*)(ws + WOHI_OFF);
  unsigned short* wolo = (unsigned short*)(ws + WOLO_OFF);

  k_prep<<<1043, 256, 0, stream>>>(Wv, Wo, wvhi, wvlo, wohi, wolo,
                                   batch, N, seg, qry, Wq, bq, q2);
  k_wk  <<<17, 256, 0, stream>>>(Wk, bk, q2, wk_eff, kbias);
  k_main<<<4096, 256, 0, stream>>>(emb, seg, wk_eff, kbias, S_ws, 1);

  // ---- PROBE: one dispatch with 4 internal repetitions into scratch.
  // Duration ~4x k_main -> surfaces in rocprof top-5 with its counters
  // (VGPR_Count for spill check, hbm_gbps for achieved BW).
  if (ws_size >= WS_PROBE) {
    unsigned short* S_dup = (unsigned short*)(ws + SDUP_OFF);
    k_main<<<4096, 256, 0, stream>>>(emb, seg, wk_eff, kbias, S_dup, 4);
  }

  dim3 g(64, 8);
  k_gemm_mfma<true ><<<g, 256, 0, stream>>>(S_ws, (size_t)4096 * 512, wvhi, wvlo, bv, attn);
  k_gemm_mfma<false><<<g, 256, 0, stream>>>(attn, 0, wohi, wolo, bo, d_out);
}

// Round 8
// 1960.618 us; speedup vs baseline: 1.3963x; 1.3918x over previous
//
#include <hip/hip_runtime.h>

#define LOG2E 1.4426950408889634f

// ---------------- ws layout (bytes) ----------------
#define WK_OFF   ((size_t)0)          // wk_eff f32 [8][512]
#define KB_OFF   ((size_t)16384)      // kbias f32 [8]
#define Q2_OFF   ((size_t)16416)      // q2 f32 [512]
#define SEG_OFF  ((size_t)18464)      // seg i32 [4097]
#define S_OFF    ((size_t)34880)      // S_ws bf16 [8][4096][512]
#define ATTN_OFF ((size_t)33589312)   // attn bf16 [4096][512]
#define WVHI_OFF ((size_t)37783616)   // Wv hi bf16 [512*512]
#define WVLO_OFF ((size_t)38307904)
#define WOHI_OFF ((size_t)38832192)
#define WOLO_OFF ((size_t)39356480)
#define WS_NEEDED ((size_t)39880768)
// probe: duplicate k_main output region (32 MB)
#define SDUP_OFF ((size_t)39880768)
#define WS_PROBE (SDUP_OFF + (size_t)8*4096*512*2)

typedef __bf16 bf16x8 __attribute__((ext_vector_type(8)));
typedef float f32x4 __attribute__((ext_vector_type(4)));

__device__ __forceinline__ float readlane_f(float v, int l) {
  return __int_as_float(__builtin_amdgcn_readlane(__float_as_int(v), l));
}

__device__ __forceinline__ unsigned short f2bf(float x) {
  unsigned u = __float_as_uint(x);
  unsigned r = (u + 0x7fffu + ((u >> 16) & 1u)) >> 16;
  return (unsigned short)r;
}

__device__ __forceinline__ unsigned pack2(float x, float y) {
  return (unsigned)f2bf(x) | ((unsigned)f2bf(y) << 16);
}

__device__ __forceinline__ float bf2f(unsigned short h) {
  return __uint_as_float((unsigned)h << 16);
}

// ---------------- K0: fused prep (W hi/lo split + seg lower_bound + q2) ----------------
__global__ __launch_bounds__(256) void k_prep(
    const float* __restrict__ Wv, const float* __restrict__ Wo,
    unsigned short* __restrict__ wvhi, unsigned short* __restrict__ wvlo,
    unsigned short* __restrict__ wohi, unsigned short* __restrict__ wolo,
    const void* __restrict__ batch, int n, int* __restrict__ seg,
    const float* __restrict__ qry, const float* __restrict__ Wq,
    const float* __restrict__ bq, float* __restrict__ q2) {
  int bx = blockIdx.x;
  if (bx < 1024) {
    int i = bx * 256 + threadIdx.x;
    float v = Wv[i];
    unsigned short h = f2bf(v);
    wvhi[i] = h;
    wvlo[i] = f2bf(v - bf2f(h));
    float o = Wo[i];
    unsigned short h2 = f2bf(o);
    wohi[i] = h2;
    wolo[i] = f2bf(o - bf2f(h2));
  } else if (bx < 1041) {
    int b = (bx - 1024) * 256 + threadIdx.x;
    if (b > 4096) return;
    const int* b32 = (const int*)batch;
    const long long* b64 = (const long long*)batch;
    bool is64 = (b32[n - 1] == 0);
    int lo = 0, hi = n;
    while (lo < hi) {
      int mid = (lo + hi) >> 1;
      long long v = is64 ? b64[mid] : (long long)b32[mid];
      if (v < (long long)b) lo = mid + 1; else hi = mid;
    }
    seg[b] = lo;
  } else {
    int d = (bx - 1041) * 256 + threadIdx.x;
    const float4* q4 = (const float4*)qry;
    const float4* w4 = (const float4*)(Wq + (size_t)d * 512);
    float acc = 0.f;
    #pragma unroll 4
    for (int j = 0; j < 128; ++j) {
      float4 a = q4[j], b = w4[j];
      acc += a.x * b.x + a.y * b.y + a.z * b.z + a.w * b.w;
    }
    q2[d] = (acc + bq[d]) * (0.125f * LOG2E);
  }
}

// ---------------- K1: wk_eff + kbias ----------------
__global__ __launch_bounds__(256) void k_wk(const float* __restrict__ Wk,
                                            const float* __restrict__ bk,
                                            const float* __restrict__ q2,
                                            float* __restrict__ wk,
                                            float* __restrict__ kb) {
  if (blockIdx.x == 16) {
    int h = threadIdx.x;
    if (h < 8) {
      float acc = 0.f;
      for (int dd = 0; dd < 64; ++dd) acc += q2[h * 64 + dd] * bk[h * 64 + dd];
      kb[h] = acc;
    }
    return;
  }
  int id = blockIdx.x * 256 + threadIdx.x;
  int h = id >> 9, e = id & 511;
  float acc = 0.f;
  #pragma unroll 4
  for (int dd = 0; dd < 64; ++dd)
    acc += q2[h * 64 + dd] * Wk[(size_t)(h * 64 + dd) * 512 + e];
  wk[id] = acc;
}

// ---------------- K2: head-split fused scores+softmax+pooling ----------------
// 4 waves per block; wave w owns heads {2w, 2w+1} and streams ALL nodes of
// graph b. Fixed regs: 4 float4 weights + 4 float4 accumulators. The 4 waves
// load identical lines (L1/MSHR coalesces). No LDS, no __syncthreads.
// 2-deep prefetch, clamped index (branch-free rotation).

#define PREF(T, B0, B1)                          \
  {                                              \
    int i_ = s + (T);                            \
    i_ = i_ < em1 ? i_ : em1;                    \
    size_t o_ = (size_t)i_ * 128 + lane;         \
    B0 = emb4[o_];                               \
    B1 = emb4[o_ + 64];                          \
  }

#define PROC(X0, X1)                                                            \
  {                                                                             \
    float p0 = X0.x * w0a.x + X0.y * w0a.y + X0.z * w0a.z + X0.w * w0a.w +      \
               X1.x * w0b.x + X1.y * w0b.y + X1.z * w0b.z + X1.w * w0b.w;       \
    float p1 = X0.x * w1a.x + X0.y * w1a.y + X0.z * w1a.z + X0.w * w1a.w +      \
               X1.x * w1b.x + X1.y * w1b.y + X1.z * w1b.z + X1.w * w1b.w;       \
    float keep = (lane & 1) ? p1 : p0;                                          \
    float send = (lane & 1) ? p0 : p1;                                          \
    float q = keep + __shfl_xor(send, 1);                                       \
    q += __shfl_xor(q, 2);                                                      \
    q += __shfl_xor(q, 4);                                                      \
    q += __shfl_xor(q, 8);                                                      \
    q += __shfl_xor(q, 16);                                                     \
    q += __shfl_xor(q, 32);                                                     \
    float wv = exp2f(q + kbsel);                                                \
    float w0_ = readlane_f(wv, 0);                                              \
    float w1_ = readlane_f(wv, 1);                                              \
    dn0 += w0_;                                                                 \
    dn1 += w1_;                                                                 \
    S0a.x += w0_ * X0.x; S0a.y += w0_ * X0.y; S0a.z += w0_ * X0.z; S0a.w += w0_ * X0.w; \
    S0b.x += w0_ * X1.x; S0b.y += w0_ * X1.y; S0b.z += w0_ * X1.z; S0b.w += w0_ * X1.w; \
    S1a.x += w1_ * X0.x; S1a.y += w1_ * X0.y; S1a.z += w1_ * X0.z; S1a.w += w1_ * X0.w; \
    S1b.x += w1_ * X1.x; S1b.y += w1_ * X1.y; S1b.z += w1_ * X1.z; S1b.w += w1_ * X1.w; \
  }

__global__ __launch_bounds__(256, 4) void k_main(const float* __restrict__ emb,
                                                 const int* __restrict__ seg,
                                                 const float* __restrict__ wk,
                                                 const float* __restrict__ kb,
                                                 unsigned short* __restrict__ S_out,
                                                 int reps) {
  const int tid = threadIdx.x;
  const int lane = tid & 63, wave = tid >> 6;
  const int b = blockIdx.x;
  const int s = seg[b], e2 = seg[b + 1];
  const int nt = e2 - s;
  const int em1 = e2 - 1;
  const int h0 = wave * 2, h1 = h0 + 1;

  const float4 w0a = *(const float4*)(wk + h0 * 512 + 4 * lane);
  const float4 w0b = *(const float4*)(wk + h0 * 512 + 256 + 4 * lane);
  const float4 w1a = *(const float4*)(wk + h1 * 512 + 4 * lane);
  const float4 w1b = *(const float4*)(wk + h1 * 512 + 256 + 4 * lane);
  const float kbsel = kb[h0 + (lane & 1)];

  const float4* emb4 = (const float4*)emb;

  for (int rep = 0; rep < reps; ++rep) {
    float4 S0a = make_float4(0.f, 0.f, 0.f, 0.f);
    float4 S0b = make_float4(0.f, 0.f, 0.f, 0.f);
    float4 S1a = make_float4(0.f, 0.f, 0.f, 0.f);
    float4 S1b = make_float4(0.f, 0.f, 0.f, 0.f);
    float dn0 = 0.f, dn1 = 0.f;

    if (nt > 0) {
      float4 A0, A1, B0, B1, C0, C1;
      PREF(0, A0, A1);
      PREF(1, B0, B1);
      int t = 0;
      while (true) {
        if (t >= nt) break;
        PREF(t + 2, C0, C1);
        PROC(A0, A1);
        ++t;
        if (t >= nt) break;
        PREF(t + 2, A0, A1);
        PROC(B0, B1);
        ++t;
        if (t >= nt) break;
        PREF(t + 2, B0, B1);
        PROC(C0, C1);
        ++t;
      }
    }

    const float i0 = dn0 > 0.f ? 1.f / dn0 : 0.f;
    const float i1 = dn1 > 0.f ? 1.f / dn1 : 0.f;
    unsigned short* p0 = S_out + ((size_t)h0 * 4096 + b) * 512;
    unsigned short* p1 = S_out + ((size_t)h1 * 4096 + b) * 512;
    uint2 v;
    v.x = pack2(S0a.x * i0, S0a.y * i0);
    v.y = pack2(S0a.z * i0, S0a.w * i0);
    *(uint2*)(p0 + 4 * lane) = v;
    v.x = pack2(S0b.x * i0, S0b.y * i0);
    v.y = pack2(S0b.z * i0, S0b.w * i0);
    *(uint2*)(p0 + 256 + 4 * lane) = v;
    v.x = pack2(S1a.x * i1, S1a.y * i1);
    v.y = pack2(S1a.z * i1, S1a.w * i1);
    *(uint2*)(p1 + 4 * lane) = v;
    v.x = pack2(S1b.x * i1, S1b.y * i1);
    v.y = pack2(S1b.z * i1, S1b.w * i1);
    *(uint2*)(p1 + 256 + 4 * lane) = v;
  }
}

// ---------------- K3/K4: MFMA NT GEMM ----------------
template <bool C_BF16>
__global__ __launch_bounds__(256) void k_gemm_mfma(
    const unsigned short* __restrict__ A, size_t a_cb_stride,
    const unsigned short* __restrict__ Whi, const unsigned short* __restrict__ Wlo,
    const float* __restrict__ bias, void* __restrict__ Cv) {
  const int t = threadIdx.x;
  const int lane = t & 63, wvid = t >> 6;
  const int wr = wvid >> 1, wc = wvid & 1;
  const int row16 = lane & 15;
  const int k8 = (lane >> 4) * 8;
  const int mbase = blockIdx.x * 64 + wr * 32;
  const int nbase = blockIdx.y * 64 + wc * 32;

  const unsigned short* Ap = A + (size_t)blockIdx.y * a_cb_stride +
                             (size_t)(mbase + row16) * 512 + k8;
  const unsigned short* Wh = Whi + (size_t)(nbase + row16) * 512 + k8;
  const unsigned short* Wl = Wlo + (size_t)(nbase + row16) * 512 + k8;

  f32x4 acc[2][2] = {};

  #pragma unroll 4
  for (int kk = 0; kk < 512; kk += 32) {
    bf16x8 a0 = *(const bf16x8*)(Ap + kk);
    bf16x8 a1 = *(const bf16x8*)(Ap + 16 * 512 + kk);
    bf16x8 h0 = *(const bf16x8*)(Wh + kk);
    bf16x8 h1 = *(const bf16x8*)(Wh + 16 * 512 + kk);
    bf16x8 l0 = *(const bf16x8*)(Wl + kk);
    bf16x8 l1 = *(const bf16x8*)(Wl + 16 * 512 + kk);
    acc[0][0] = __builtin_amdgcn_mfma_f32_16x16x32_bf16(a0, h0, acc[0][0], 0, 0, 0);
    acc[0][1] = __builtin_amdgcn_mfma_f32_16x16x32_bf16(a0, h1, acc[0][1], 0, 0, 0);
    acc[1][0] = __builtin_amdgcn_mfma_f32_16x16x32_bf16(a1, h0, acc[1][0], 0, 0, 0);
    acc[1][1] = __builtin_amdgcn_mfma_f32_16x16x32_bf16(a1, h1, acc[1][1], 0, 0, 0);
    acc[0][0] = __builtin_amdgcn_mfma_f32_16x16x32_bf16(a0, l0, acc[0][0], 0, 0, 0);
    acc[0][1] = __builtin_amdgcn_mfma_f32_16x16x32_bf16(a0, l1, acc[0][1], 0, 0, 0);
    acc[1][0] = __builtin_amdgcn_mfma_f32_16x16x32_bf16(a1, l0, acc[1][0], 0, 0, 0);
    acc[1][1] = __builtin_amdgcn_mfma_f32_16x16x32_bf16(a1, l1, acc[1][1], 0, 0, 0);
  }

  const int r4 = (lane >> 4) * 4;
  #pragma unroll
  for (int c = 0; c < 2; ++c) {
    const float bc = bias[nbase + c * 16 + row16];
    #pragma unroll
    for (int r = 0; r < 2; ++r) {
      #pragma unroll
      for (int j = 0; j < 4; ++j) {
        float v = acc[r][c][j] + bc;
        size_t row = (size_t)(mbase + r * 16 + r4 + j);
        size_t col = (size_t)(nbase + c * 16 + row16);
        if (C_BF16)
          ((unsigned short*)Cv)[row * 512 + col] = f2bf(v);
        else
          ((float*)Cv)[row * 512 + col] = v;
      }
    }
  }
}

// ---------------- launcher ----------------
extern "C" void kernel_launch(void* const* d_in, const int* in_sizes, int n_in,
                              void* d_out, int out_size, void* d_ws, size_t ws_size,
                              hipStream_t stream) {
  const float* emb   = (const float*)d_in[0];
  const void*  batch = d_in[1];
  const float* qry   = (const float*)d_in[2];
  const float* Wq    = (const float*)d_in[3];
  const float* bq    = (const float*)d_in[4];
  const float* Wk    = (const float*)d_in[5];
  const float* bk    = (const float*)d_in[6];
  const float* Wv    = (const float*)d_in[7];
  const float* bv    = (const float*)d_in[8];
  const float* Wo    = (const float*)d_in[9];
  const float* bo    = (const float*)d_in[10];
  const int N = in_sizes[1];

  if (ws_size < WS_NEEDED) return;

  char* ws = (char*)d_ws;
  float* wk_eff = (float*)(ws + WK_OFF);
  float* kbias  = (float*)(ws + KB_OFF);
  float* q2     = (float*)(ws + Q2_OFF);
  int*   seg    = (int*)(ws + SEG_OFF);
  unsigned short* S_ws = (unsigned short*)(ws + S_OFF);
  unsigned short* attn = (unsigned short*)(ws + ATTN_OFF);
  unsigned short* wvhi = (unsigned short*)(ws + WVHI_OFF);
  unsigned short* wvlo = (unsigned short*)(ws + WVLO_OFF);
  unsigned short* wohi = (unsigned short*)(ws + WOHI_OFF);
  unsigned short* wolo = (unsigned short*)(ws + WOLO_OFF);

  k_prep<<<1043, 256, 0, stream>>>(Wv, Wo, wvhi, wvlo, wohi, wolo,
                                   batch, N, seg, qry, Wq, bq, q2);
  k_wk  <<<17, 256, 0, stream>>>(Wk, bk, q2, wk_eff, kbias);
  k_main<<<4096, 256, 0, stream>>>(emb, seg, wk_eff, kbias, S_ws, 1);

  // ---- PROBE: one dispatch, 4 internal reps into scratch. Surfaces in
  // rocprof top-5 with k_main's true VGPR/WRITE_SIZE (spill check) and BW.
  if (ws_size >= WS_PROBE) {
    unsigned short* S_dup = (unsigned short*)(ws + SDUP_OFF);
    k_main<<<4096, 256, 0, stream>>>(emb, seg, wk_eff, kbias, S_dup, 4);
  }

  dim3 g(64, 8);
  k_gemm_mfma<true ><<<g, 256, 0, stream>>>(S_ws, (size_t)4096 * 512, wvhi, wvlo, bv, attn);
  k_gemm_mfma<false><<<g, 256, 0, stream>>>(attn, 0, wohi, wolo, bo, d_out);
}